// Round 6
// baseline (128.600 us; speedup 1.0000x reference)
//
#include <hip/hip_runtime.h>
#include <hip/hip_bf16.h>
#include <cstdint>

#define BATCH  8192
#define INDIM  1024   // K (elements == bytes in fp8)
#define OUTDIM 2048   // N

typedef float  f32x4   __attribute__((ext_vector_type(4)));
typedef float  f32x16  __attribute__((ext_vector_type(16)));
typedef int    i32x2   __attribute__((ext_vector_type(2)));
typedef int    i32x4   __attribute__((ext_vector_type(4)));
typedef int    i32x8   __attribute__((ext_vector_type(8)));

// pack 4 floats -> 4 fp8 e4m3 bytes (chip-native format; MFMA consumes same)
__device__ __forceinline__ uint32_t pk_fp8x4(float a, float b, float c, float d) {
    uint32_t v = 0;
    v = __builtin_amdgcn_cvt_pk_fp8_f32(a, b, v, false);  // bytes 0,1
    v = __builtin_amdgcn_cvt_pk_fp8_f32(c, d, v, true);   // bytes 2,3
    return v;
}

// async global->LDS, 16B per lane. LDS dest is wave-uniform base + lane*16.
__device__ __forceinline__ void async_copy16(const void* g, void* l) {
    __builtin_amdgcn_global_load_lds(
        (__attribute__((address_space(1))) void*)(g),
        (__attribute__((address_space(3))) void*)(l),
        16, 0, 0);
}

// 16B-pair swizzle key (fp8 row = 64 B = 4 pairs): rows 1,4 apart differ
__device__ __forceinline__ int k4(int r) { return (r ^ (r >> 2)) & 3; }

// ------------- fused prep: x->fp8+xsq (blocks 0..2047), P->Pt (2048..2303) --
// prep_x: one wave per row, 4 rows/block; xsq exact fp32.
// prep_p: P (fp32 [K][O]) -> Pt fp8(32*P) [O][K] + psq_part[4][O]; the *32
// scale is a power of 2 (exact); epilogue multiplies acc by 1/16.
// Fusion: prep_p (~2us) runs concurrently under prep_x (~6.5us), one launch.
__global__ __launch_bounds__(256) void prep_fused(const float* __restrict__ x,
                                                  const float* __restrict__ P,
                                                  uint8_t* __restrict__ xq8,
                                                  float* __restrict__ xsq,
                                                  uint8_t* __restrict__ pt8,
                                                  float* __restrict__ psq_part) {
    __shared__ float tile[64][33];
    __shared__ float psums[32];
    const int tid = threadIdx.x;

    if (blockIdx.x < BATCH / 4) {
        // ---- prep_x ----
        const int wave = tid >> 6;
        const int lane = tid & 63;
        const int row  = blockIdx.x * 4 + wave;
        const f32x4* src = (const f32x4*)(x + (size_t)row * INDIM);
        uint32_t* dst = (uint32_t*)(xq8 + (size_t)row * INDIM);
        float s = 0.f;
#pragma unroll
        for (int w = 0; w < 4; ++w) {
            const f32x4 v = src[lane + w * 64];
            s += v.x * v.x + v.y * v.y + v.z * v.z + v.w * v.w;
            dst[lane + w * 64] = pk_fp8x4(v.x, v.y, v.z, v.w);
        }
#pragma unroll
        for (int off = 32; off > 0; off >>= 1) s += __shfl_down(s, off);
        if (lane == 0) xsq[row] = s;
        return;
    }

    // ---- prep_p ----
    const int bx   = blockIdx.x - BATCH / 4;   // 0..255
    const int o0   = (bx & 63) * 32;
    const int kblk = bx >> 6;                  // 0..3
    const int k0   = kblk * 256;
    const int kk   = tid >> 3;         // 0..31 (load row within half-tile)
    const int oq   = tid & 7;          // 0..7  (float4 col group)
    const int so   = tid >> 3;         // 0..31 (store col)
    const int skc  = (tid & 7) * 8;    // 0..56 (store k base)
    float a4[4] = {0.f, 0.f, 0.f, 0.f};
    if (tid < 32) psums[tid] = 0.f;
    for (int st = 0; st < 4; ++st) {
        __syncthreads();   // tile reuse guard (st=0: covers psums init)
#pragma unroll
        for (int r2 = 0; r2 < 2; ++r2) {
            const int k = r2 * 32 + kk;
            const float4 v = *(const float4*)(P + (size_t)(k0 + st * 64 + k) * OUTDIM + o0 + oq * 4);
            tile[k][oq * 4 + 0] = v.x;
            tile[k][oq * 4 + 1] = v.y;
            tile[k][oq * 4 + 2] = v.z;
            tile[k][oq * 4 + 3] = v.w;
            a4[0] += v.x * v.x; a4[1] += v.y * v.y;
            a4[2] += v.z * v.z; a4[3] += v.w * v.w;
        }
        __syncthreads();
        i32x2 w;
        w.x = pk_fp8x4(tile[skc + 0][so] * 32.f, tile[skc + 1][so] * 32.f,
                       tile[skc + 2][so] * 32.f, tile[skc + 3][so] * 32.f);
        w.y = pk_fp8x4(tile[skc + 4][so] * 32.f, tile[skc + 5][so] * 32.f,
                       tile[skc + 6][so] * 32.f, tile[skc + 7][so] * 32.f);
        *(i32x2*)(pt8 + (size_t)(o0 + so) * INDIM + k0 + st * 64 + skc) = w;
    }
#pragma unroll
    for (int e = 0; e < 4; ++e) atomicAdd(&psums[oq * 4 + e], a4[e]);
    __syncthreads();
    if (tid < 32) psq_part[(size_t)kblk * OUTDIM + o0 + tid] = psums[tid];
}

// ---------------- main GEMM + epilogue --------------------------------------
// C[m][n] = (1/16) * sum_k x8[m][k] * p8[n][k] - xsq[m] - psq[n]
//
// 256x256 tile, BK=64 bytes, 8 waves (2m x 4n), 512 threads; wave = 128x64
// output via 4x2 frags of MX-scaled MFMA 32x32x64 f8f6f4 (unit E8M0 scales).
//
// R5 post-mortem: the LDS read port is the critical pipe (96 b128/iter/CU at
// ~4-way structural conflict ~ 1800cy > MFMA 1100cy). Fix: B comes STRAIGHT
// FROM GLOBAL into registers (two dwordx4/frag, prefetched one iter ahead) —
// its 256KB per-XCD slice is L2-resident via the XCD swizzle. Wave LDS reads
// drop 12->8 b128, staging writes halve. A stays LDS-staged (k4-swizzled,
// double-buffered, rolled loop — known-good R4/R5 skeleton).
#define TM 256
#define TN 256
#define BKB 64

__global__ __launch_bounds__(512, 2) void gemm_ep(const uint8_t* __restrict__ xq8,
                                                  const uint8_t* __restrict__ pt8,
                                                  const float* __restrict__ xsq,
                                                  const float* __restrict__ psq_part,
                                                  float* __restrict__ out) {
    __shared__ __align__(16) uint8_t As[2][TM * BKB];   // 2 x 16 KB

    const int tid  = threadIdx.x;
    // XCD swizzle: consecutive hw blockIdx round-robin over 8 XCDs; give each
    // XCD one full n-column (32 m-blocks) so its B-slice stays in its L2.
    const int nb   = blockIdx.x & 7;    // n-block 0..7
    const int mb   = blockIdx.x >> 3;   // m-block 0..31
    const int m0   = mb * TM;
    const int n0   = nb * TN;
    const int wave = tid >> 6;          // 0..7
    const int lane = tid & 63;
    const int wm   = (wave >> 2) * 128; // 2 wave-rows
    const int wn   = (wave & 3) * 64;   // 4 wave-cols
    const int l31  = lane & 31;
    const int half = lane >> 5;

    // A staging geometry (invariant): 1024 slots/buffer, 512 threads -> 2 each
    const int sr0 = tid >> 2;                 // slot0 row (0..127)
    const int sq0 = (tid & 3) ^ k4(sr0);      // slot0 global 16B pair
    const int sr1 = sr0 + 128;                // slot1 row (128..255)
    const int sq1 = (tid & 3) ^ k4(sr1);      // slot1 global 16B pair

    // B: per-lane base pointers (row wn+j*32+l31, k-bytes half*32 + 0..31)
    const uint8_t* bp0 = pt8 + (size_t)(n0 + wn + l31) * INDIM + half * 32;
    const uint8_t* bp1 = pt8 + (size_t)(n0 + wn + 32 + l31) * INDIM + half * 32;

    f32x16 acc[4][2];
#pragma unroll
    for (int i = 0; i < 4; ++i)
#pragma unroll
        for (int j = 0; j < 2; ++j)
#pragma unroll
            for (int e = 0; e < 16; ++e) acc[i][j][e] = 0.f;

    // prologue: stage A buf0 (K-block 0), load B frags for K-block 0
    async_copy16(xq8 + (size_t)(m0 + sr0) * INDIM + sq0 * 16, &As[0][tid * 16]);
    async_copy16(xq8 + (size_t)(m0 + sr1) * INDIM + sq1 * 16, &As[0][(512 + tid) * 16]);
    i32x8 bv[2];
    {
        const i32x4 l0 = *(const i32x4*)(bp0);
        const i32x4 h0 = *(const i32x4*)(bp0 + 16);
        bv[0] = __builtin_shufflevector(l0, h0, 0, 1, 2, 3, 4, 5, 6, 7);
        const i32x4 l1 = *(const i32x4*)(bp1);
        const i32x4 h1 = *(const i32x4*)(bp1 + 16);
        bv[1] = __builtin_shufflevector(l1, h1, 0, 1, 2, 3, 4, 5, 6, 7);
    }
    __syncthreads();

    int cur = 0;
    for (int kb = 0; kb < INDIM; kb += BKB) {
        const bool more = (kb + BKB < INDIM);
        i32x8 bvn[2];
        if (more) {
            const int nxt = cur ^ 1;
            const int kn  = kb + BKB;
            // issue next A staging + next B reg-loads first — both drain
            // under this iteration's ds_read+MFMA
            async_copy16(xq8 + (size_t)(m0 + sr0) * INDIM + kn + sq0 * 16, &As[nxt][tid * 16]);
            async_copy16(xq8 + (size_t)(m0 + sr1) * INDIM + kn + sq1 * 16, &As[nxt][(512 + tid) * 16]);
            const i32x4 l0 = *(const i32x4*)(bp0 + kn);
            const i32x4 h0 = *(const i32x4*)(bp0 + kn + 16);
            bvn[0] = __builtin_shufflevector(l0, h0, 0, 1, 2, 3, 4, 5, 6, 7);
            const i32x4 l1 = *(const i32x4*)(bp1 + kn);
            const i32x4 h1 = *(const i32x4*)(bp1 + kn + 16);
            bvn[1] = __builtin_shufflevector(l1, h1, 0, 1, 2, 3, 4, 5, 6, 7);
        }

        // A frags from LDS: full 32B K-fragment (global chunks 2h, 2h+1)
        i32x8 av[4];
#pragma unroll
        for (int i = 0; i < 4; ++i) {
            const int r = wm + i * 32 + l31;
            const uint8_t* base = &As[cur][r * BKB];
            const i32x4 lo = *(const i32x4*)(base + (((half << 1) | 0) ^ k4(r)) * 16);
            const i32x4 hi = *(const i32x4*)(base + (((half << 1) | 1) ^ k4(r)) * 16);
            av[i] = __builtin_shufflevector(lo, hi, 0, 1, 2, 3, 4, 5, 6, 7);
        }
#pragma unroll
        for (int i = 0; i < 4; ++i)
#pragma unroll
            for (int j = 0; j < 2; ++j)
                acc[i][j] = __builtin_amdgcn_mfma_scale_f32_32x32x64_f8f6f4(
                    av[i], bv[j], acc[i][j],
                    0 /*A fmt: fp8 e4m3*/, 0 /*B fmt: fp8 e4m3*/,
                    0, 0x7F7F7F7F /*scale_a = 1.0*/,
                    0, 0x7F7F7F7F /*scale_b = 1.0*/);

        // drain prefetch (overlapped with compute above) + guard buffer reuse
        __syncthreads();
        if (more) { bv[0] = bvn[0]; bv[1] = bvn[1]; }
        cur ^= 1;
    }

    // epilogue: C/D layout col = lane&31, row = (reg&3) + 8*(reg>>2) + 4*half
    // (shape-determined, dtype-independent — guide §3). scale: 2*cross = acc/16
    const float* xsq_w = xsq + m0 + wm;
    float ps[2];
#pragma unroll
    for (int j = 0; j < 2; ++j) {
        const int n = n0 + wn + j * 32 + l31;
        ps[j] = psq_part[n] + psq_part[OUTDIM + n] +
                psq_part[2 * OUTDIM + n] + psq_part[3 * OUTDIM + n];
    }
#pragma unroll
    for (int i = 0; i < 4; ++i) {
#pragma unroll
        for (int rg = 0; rg < 16; ++rg) {
            const int rloc = (rg & 3) + 8 * (rg >> 2) + 4 * half;
            const float xs = xsq_w[i * 32 + rloc];
            float* orow = out + (size_t)(m0 + wm + i * 32 + rloc) * OUTDIM + n0 + wn + l31;
#pragma unroll
            for (int j = 0; j < 2; ++j)
                orow[j * 32] = 0.0625f * acc[i][j][rg] - xs - ps[j];
        }
    }
}

// ---------------- fallback (only if workspace is too small) -----------------
__global__ void fallback_kernel(const float* __restrict__ x,
                                const float* __restrict__ P,
                                float* __restrict__ out) {
    const int o = blockIdx.x * blockDim.x + threadIdx.x;
    const int b = blockIdx.y;
    float cr = 0.f, xq = 0.f, pq = 0.f;
    for (int i = 0; i < INDIM; ++i) {
        const float xv = x[(size_t)b * INDIM + i];
        const float pv = P[(size_t)i * OUTDIM + o];
        cr += xv * pv; xq += xv * xv; pq += pv * pv;
    }
    out[(size_t)b * OUTDIM + o] = 2.f * cr - xq - pq;
}

extern "C" void kernel_launch(void* const* d_in, const int* in_sizes, int n_in,
                              void* d_out, int out_size, void* d_ws, size_t ws_size,
                              hipStream_t stream) {
    (void)in_sizes; (void)n_in; (void)out_size;
    const float* x = (const float*)d_in[0];
    const float* P = (const float*)d_in[1];
    float* out = (float*)d_out;

    const size_t xq_bytes  = (size_t)BATCH * INDIM;        // 8 MB
    const size_t pt_bytes  = (size_t)OUTDIM * INDIM;       // 2 MB
    const size_t xsq_bytes = (size_t)BATCH * 4;            // 32 KB
    const size_t psq_bytes = (size_t)4 * OUTDIM * 4;       // 32 KB
    const size_t need = xq_bytes + pt_bytes + xsq_bytes + psq_bytes;

    if (ws_size < need) {
        fallback_kernel<<<dim3(OUTDIM / 256, BATCH), 256, 0, stream>>>(x, P, out);
        return;
    }

    uint8_t* xq8      = (uint8_t*)d_ws;
    uint8_t* pt8      = (uint8_t*)d_ws + xq_bytes;
    float*   xsq      = (float*)((char*)d_ws + xq_bytes + pt_bytes);
    float*   psq_part = xsq + BATCH;

    prep_fused<<<BATCH / 4 + (OUTDIM / 32) * (INDIM / 256), 256, 0, stream>>>(
        x, P, xq8, xsq, pt8, psq_part);
    gemm_ep<<<(BATCH / TM) * (OUTDIM / TN), 512, 0, stream>>>(xq8, pt8, xsq, psq_part, out);
}

// Round 7
// 116.041 us; speedup vs baseline: 1.1082x; 1.1082x over previous
//
#include <hip/hip_runtime.h>
#include <hip/hip_bf16.h>
#include <cstdint>

#define BATCH  8192
#define INDIM  1024   // K (elements == bytes in fp8)
#define OUTDIM 2048   // N

typedef float  f32x4   __attribute__((ext_vector_type(4)));
typedef float  f32x16  __attribute__((ext_vector_type(16)));
typedef int    i32x2   __attribute__((ext_vector_type(2)));
typedef int    i32x4   __attribute__((ext_vector_type(4)));
typedef int    i32x8   __attribute__((ext_vector_type(8)));

// pack 4 floats -> 4 fp8 e4m3 bytes (chip-native format; MFMA consumes same)
__device__ __forceinline__ uint32_t pk_fp8x4(float a, float b, float c, float d) {
    uint32_t v = 0;
    v = __builtin_amdgcn_cvt_pk_fp8_f32(a, b, v, false);  // bytes 0,1
    v = __builtin_amdgcn_cvt_pk_fp8_f32(c, d, v, true);   // bytes 2,3
    return v;
}

// async global->LDS, 16B per lane. LDS dest is wave-uniform base + lane*16.
__device__ __forceinline__ void async_copy16(const void* g, void* l) {
    __builtin_amdgcn_global_load_lds(
        (__attribute__((address_space(1))) void*)(g),
        (__attribute__((address_space(3))) void*)(l),
        16, 0, 0);
}

// 16B-chunk swizzle key for 128B rows (8 chunks): rows 1 and 8 apart differ;
// uniform over 32 consecutive rows -> bank-uniform frag reads AND staging.
__device__ __forceinline__ int k8(int r) { return (r ^ (r >> 3)) & 7; }

// ------------- fused prep: x->fp8+xsq (blocks 0..2047), P->Pt (2048..2303) --
// prep_x: one wave per row, 4 rows/block; xsq exact fp32.
// prep_p: P (fp32 [K][O]) -> Pt fp8(32*P) [O][K] + psq_part[4][O]; the *32
// scale is a power of 2 (exact); epilogue multiplies acc by 1/16.
__global__ __launch_bounds__(256) void prep_fused(const float* __restrict__ x,
                                                  const float* __restrict__ P,
                                                  uint8_t* __restrict__ xq8,
                                                  float* __restrict__ xsq,
                                                  uint8_t* __restrict__ pt8,
                                                  float* __restrict__ psq_part) {
    __shared__ float tile[64][33];
    __shared__ float psums[32];
    const int tid = threadIdx.x;

    if (blockIdx.x < BATCH / 4) {
        // ---- prep_x ----
        const int wave = tid >> 6;
        const int lane = tid & 63;
        const int row  = blockIdx.x * 4 + wave;
        const f32x4* src = (const f32x4*)(x + (size_t)row * INDIM);
        uint32_t* dst = (uint32_t*)(xq8 + (size_t)row * INDIM);
        float s = 0.f;
#pragma unroll
        for (int w = 0; w < 4; ++w) {
            const f32x4 v = src[lane + w * 64];
            s += v.x * v.x + v.y * v.y + v.z * v.z + v.w * v.w;
            dst[lane + w * 64] = pk_fp8x4(v.x, v.y, v.z, v.w);
        }
#pragma unroll
        for (int off = 32; off > 0; off >>= 1) s += __shfl_down(s, off);
        if (lane == 0) xsq[row] = s;
        return;
    }

    // ---- prep_p ----
    const int bx   = blockIdx.x - BATCH / 4;   // 0..255
    const int o0   = (bx & 63) * 32;
    const int kblk = bx >> 6;                  // 0..3
    const int k0   = kblk * 256;
    const int kk   = tid >> 3;         // 0..31 (load row within half-tile)
    const int oq   = tid & 7;          // 0..7  (float4 col group)
    const int so   = tid >> 3;         // 0..31 (store col)
    const int skc  = (tid & 7) * 8;    // 0..56 (store k base)
    float a4[4] = {0.f, 0.f, 0.f, 0.f};
    if (tid < 32) psums[tid] = 0.f;
    for (int st = 0; st < 4; ++st) {
        __syncthreads();   // tile reuse guard (st=0: covers psums init)
#pragma unroll
        for (int r2 = 0; r2 < 2; ++r2) {
            const int k = r2 * 32 + kk;
            const float4 v = *(const float4*)(P + (size_t)(k0 + st * 64 + k) * OUTDIM + o0 + oq * 4);
            tile[k][oq * 4 + 0] = v.x;
            tile[k][oq * 4 + 1] = v.y;
            tile[k][oq * 4 + 2] = v.z;
            tile[k][oq * 4 + 3] = v.w;
            a4[0] += v.x * v.x; a4[1] += v.y * v.y;
            a4[2] += v.z * v.z; a4[3] += v.w * v.w;
        }
        __syncthreads();
        i32x2 w;
        w.x = pk_fp8x4(tile[skc + 0][so] * 32.f, tile[skc + 1][so] * 32.f,
                       tile[skc + 2][so] * 32.f, tile[skc + 3][so] * 32.f);
        w.y = pk_fp8x4(tile[skc + 4][so] * 32.f, tile[skc + 5][so] * 32.f,
                       tile[skc + 6][so] * 32.f, tile[skc + 7][so] * 32.f);
        *(i32x2*)(pt8 + (size_t)(o0 + so) * INDIM + k0 + st * 64 + skc) = w;
    }
#pragma unroll
    for (int e = 0; e < 4; ++e) atomicAdd(&psums[oq * 4 + e], a4[e]);
    __syncthreads();
    if (tid < 32) psq_part[(size_t)kblk * OUTDIM + o0 + tid] = psums[tid];
}

// ---------------- main GEMM + epilogue --------------------------------------
// C[m][n] = (1/16) * sum_k x8[m][k] * p8[n][k] - xsq[m] - psq[n]
//
// 256x256 tile, BK=128 bytes, 8 waves (2m x 4n), 512 threads; wave = 128x64
// output via 4x2 frags of MX-scaled MFMA 32x32x64 f8f6f4 (unit E8M0 scales),
// 2 K-instr per frag-pair per iter (ks=0,1).
//
// R6 post-mortem: B-from-global regressed 10.8us (1024B-strided per-lane
// loads shatter into 32 cache lines/instr) — B is back in LDS. BK=128
// halves the iteration count (16->8) and thus the per-iter barrier+drain
// overhead of the 2-phase loop; LDS 128KB double-buffered (m201-template
// size), still 1 block/CU, no occupancy change. Frags re-read per ks inside
// the iter keep VGPR ~210 < 256 cap. gemm floor is the 67MB output write
// (~10.7us at achievable BW).
//
// LDS 16B-chunk c_lds holds global chunk c_lds ^ k8(row) — bank-uniform for
// both the linear staging writes and the per-ks frag reads.
#define TM 256
#define TN 256
#define BKB 128

__global__ __launch_bounds__(512, 2) void gemm_ep(const uint8_t* __restrict__ xq8,
                                                  const uint8_t* __restrict__ pt8,
                                                  const float* __restrict__ xsq,
                                                  const float* __restrict__ psq_part,
                                                  float* __restrict__ out) {
    __shared__ __align__(16) uint8_t As[2][TM * BKB];   // 2 x 32 KB
    __shared__ __align__(16) uint8_t Bs[2][TN * BKB];   // 2 x 32 KB

    const int tid  = threadIdx.x;
    // XCD swizzle: consecutive hw blockIdx round-robin over 8 XCDs; give each
    // XCD one full n-column (32 m-blocks) so its B-slice stays in its L2.
    const int nb   = blockIdx.x & 7;    // n-block 0..7
    const int mb   = blockIdx.x >> 3;   // m-block 0..31
    const int m0   = mb * TM;
    const int n0   = nb * TN;
    const int wave = tid >> 6;          // 0..7
    const int lane = tid & 63;
    const int wm   = (wave >> 2) * 128; // 2 wave-rows
    const int wn   = (wave & 3) * 64;   // 4 wave-cols
    const int l31  = lane & 31;
    const int half = lane >> 5;

    // staging geometry: 2048 16B-slots per matrix per buffer, 4 per thread.
    // slot id = s*512+tid: row = id>>3, c_lds = id&7 (=tid&7), src chunk
    // c_g = c_lds ^ k8(row). Wave lanes -> consecutive ids -> linear LDS dest.
    int srow[4], scg[4];
#pragma unroll
    for (int s = 0; s < 4; ++s) {
        srow[s] = s * 64 + (tid >> 3);
        scg[s]  = (tid & 7) ^ k8(srow[s]);
    }

    f32x16 acc[4][2];
#pragma unroll
    for (int i = 0; i < 4; ++i)
#pragma unroll
        for (int j = 0; j < 2; ++j)
#pragma unroll
            for (int e = 0; e < 16; ++e) acc[i][j][e] = 0.f;

    // prologue: fill buf 0 with K-block 0
#pragma unroll
    for (int s = 0; s < 4; ++s) {
        async_copy16(xq8 + (size_t)(m0 + srow[s]) * INDIM + scg[s] * 16,
                     &As[0][(s * 512 + tid) * 16]);
        async_copy16(pt8 + (size_t)(n0 + srow[s]) * INDIM + scg[s] * 16,
                     &Bs[0][(s * 512 + tid) * 16]);
    }
    __syncthreads();

    int cur = 0;
    for (int kb = 0; kb < INDIM; kb += BKB) {
        // issue next tile's loads first — they drain under this tile's compute
        if (kb + BKB < INDIM) {
            const int nxt = cur ^ 1;
            const int kn  = kb + BKB;
#pragma unroll
            for (int s = 0; s < 4; ++s) {
                async_copy16(xq8 + (size_t)(m0 + srow[s]) * INDIM + kn + scg[s] * 16,
                             &As[nxt][(s * 512 + tid) * 16]);
                async_copy16(pt8 + (size_t)(n0 + srow[s]) * INDIM + kn + scg[s] * 16,
                             &Bs[nxt][(s * 512 + tid) * 16]);
            }
        }

#pragma unroll
        for (int ks = 0; ks < 2; ++ks) {
            const int cbase = ks * 4 + half * 2;  // global chunk base for lane
            i32x8 av[4], bv[2];
#pragma unroll
            for (int i = 0; i < 4; ++i) {
                const int r = wm + i * 32 + l31;
                const uint8_t* base = &As[cur][r * BKB];
                const i32x4 lo = *(const i32x4*)(base + ((cbase + 0) ^ k8(r)) * 16);
                const i32x4 hi = *(const i32x4*)(base + ((cbase + 1) ^ k8(r)) * 16);
                av[i] = __builtin_shufflevector(lo, hi, 0, 1, 2, 3, 4, 5, 6, 7);
            }
#pragma unroll
            for (int j = 0; j < 2; ++j) {
                const int r = wn + j * 32 + l31;
                const uint8_t* base = &Bs[cur][r * BKB];
                const i32x4 lo = *(const i32x4*)(base + ((cbase + 0) ^ k8(r)) * 16);
                const i32x4 hi = *(const i32x4*)(base + ((cbase + 1) ^ k8(r)) * 16);
                bv[j] = __builtin_shufflevector(lo, hi, 0, 1, 2, 3, 4, 5, 6, 7);
            }
#pragma unroll
            for (int i = 0; i < 4; ++i)
#pragma unroll
                for (int j = 0; j < 2; ++j)
                    acc[i][j] = __builtin_amdgcn_mfma_scale_f32_32x32x64_f8f6f4(
                        av[i], bv[j], acc[i][j],
                        0 /*A fmt: fp8 e4m3*/, 0 /*B fmt: fp8 e4m3*/,
                        0, 0x7F7F7F7F /*scale_a = 1.0*/,
                        0, 0x7F7F7F7F /*scale_b = 1.0*/);
        }

        // drain prefetch (overlapped with compute above) + guard buffer reuse
        __syncthreads();
        cur ^= 1;
    }

    // epilogue: C/D layout col = lane&31, row = (reg&3) + 8*(reg>>2) + 4*half
    // (shape-determined, dtype-independent — guide §3). scale: 2*cross = acc/16
    const float* xsq_w = xsq + m0 + wm;
    float ps[2];
#pragma unroll
    for (int j = 0; j < 2; ++j) {
        const int n = n0 + wn + j * 32 + l31;
        ps[j] = psq_part[n] + psq_part[OUTDIM + n] +
                psq_part[2 * OUTDIM + n] + psq_part[3 * OUTDIM + n];
    }
#pragma unroll
    for (int i = 0; i < 4; ++i) {
#pragma unroll
        for (int rg = 0; rg < 16; ++rg) {
            const int rloc = (rg & 3) + 8 * (rg >> 2) + 4 * half;
            const float xs = xsq_w[i * 32 + rloc];
            float* orow = out + (size_t)(m0 + wm + i * 32 + rloc) * OUTDIM + n0 + wn + l31;
#pragma unroll
            for (int j = 0; j < 2; ++j)
                orow[j * 32] = 0.0625f * acc[i][j][rg] - xs - ps[j];
        }
    }
}

// ---------------- fallback (only if workspace is too small) -----------------
__global__ void fallback_kernel(const float* __restrict__ x,
                                const float* __restrict__ P,
                                float* __restrict__ out) {
    const int o = blockIdx.x * blockDim.x + threadIdx.x;
    const int b = blockIdx.y;
    float cr = 0.f, xq = 0.f, pq = 0.f;
    for (int i = 0; i < INDIM; ++i) {
        const float xv = x[(size_t)b * INDIM + i];
        const float pv = P[(size_t)i * OUTDIM + o];
        cr += xv * pv; xq += xv * xv; pq += pv * pv;
    }
    out[(size_t)b * OUTDIM + o] = 2.f * cr - xq - pq;
}

extern "C" void kernel_launch(void* const* d_in, const int* in_sizes, int n_in,
                              void* d_out, int out_size, void* d_ws, size_t ws_size,
                              hipStream_t stream) {
    (void)in_sizes; (void)n_in; (void)out_size;
    const float* x = (const float*)d_in[0];
    const float* P = (const float*)d_in[1];
    float* out = (float*)d_out;

    const size_t xq_bytes  = (size_t)BATCH * INDIM;        // 8 MB
    const size_t pt_bytes  = (size_t)OUTDIM * INDIM;       // 2 MB
    const size_t xsq_bytes = (size_t)BATCH * 4;            // 32 KB
    const size_t psq_bytes = (size_t)4 * OUTDIM * 4;       // 32 KB
    const size_t need = xq_bytes + pt_bytes + xsq_bytes + psq_bytes;

    if (ws_size < need) {
        fallback_kernel<<<dim3(OUTDIM / 256, BATCH), 256, 0, stream>>>(x, P, out);
        return;
    }

    uint8_t* xq8      = (uint8_t*)d_ws;
    uint8_t* pt8      = (uint8_t*)d_ws + xq_bytes;
    float*   xsq      = (float*)((char*)d_ws + xq_bytes + pt_bytes);
    float*   psq_part = xsq + BATCH;

    prep_fused<<<BATCH / 4 + (OUTDIM / 32) * (INDIM / 256), 256, 0, stream>>>(
        x, P, xq8, xsq, pt8, psq_part);
    gemm_ep<<<(BATCH / TM) * (OUTDIM / TN), 512, 0, stream>>>(xq8, pt8, xsq, psq_part, out);
}